// Round 1
// baseline (770.617 us; speedup 1.0000x reference)
//
#include <hip/hip_runtime.h>
#include <cmath>

// Problem constants (from reference): T=128, N=64, D=512, H=512
#define TT 128
#define NN 64
#define DD 512
#define HH 512
#define GG 1536  // 3*H

// ---- workspace layout (bytes) ----
// meta[0]=total tasks, meta[1]=claim counter, meta[2]=total batches
#define META_OFF   0
#define BATCH_OFF  1024            // int4 batches[<=1024]
#define TASK_OFF   32768           // int4 tasks[<=8192]
#define WT_OFF     262144          // float wT[512][1536]  (w_hh transposed), 3 MB
#define GI_OFF     4194304         // float gi[8192][1536], 50.3 MB
#define WS_NEEDED  (GI_OFF + (size_t)TT * NN * GG * 4)

// ---------------------------------------------------------------------------
// Task builder: segment the masked timeline per batch row.
// A segment starts at t=0 and at every t with mask==0 (h is zeroed there).
// Tasks are counting-sorted by length (descending), then grouped into batches:
//   len>=5 -> width 4, len 3..4 -> width 8, len<=2 -> width 16.
// Cost of a batch = maxlen * width, so long segments get narrow batches
// (short critical path) and short segments get wide ones (weight reuse).
// ---------------------------------------------------------------------------
__global__ void build_tasks(const float* __restrict__ masks,
                            int* __restrict__ meta,
                            int4* __restrict__ tasks,
                            int4* __restrict__ batches) {
  __shared__ int hist[TT + 1];
  __shared__ int offs[TT + 1];
  const int tid = threadIdx.x;  // 128 threads
  for (int i = tid; i <= TT; i += blockDim.x) hist[i] = 0;
  __syncthreads();
  if (tid < NN) {
    const int n = tid;
    int start = 0;
    for (int t = 1; t < TT; ++t) {
      if (masks[t * NN + n] == 0.0f) { atomicAdd(&hist[t - start], 1); start = t; }
    }
    atomicAdd(&hist[TT - start], 1);
  }
  __syncthreads();
  if (tid == 0) {
    int acc = 0;
    for (int l = TT; l >= 1; --l) { offs[l] = acc; acc += hist[l]; }
    meta[0] = acc;
  }
  __syncthreads();
  const int totalTasks = meta[0];
  if (tid < NN) {
    const int n = tid;
    int start = 0;
    for (int t = 1; t < TT; ++t) {
      if (masks[t * NN + n] == 0.0f) {
        const int len = t - start;
        const int pos = atomicAdd(&offs[len], 1);
        const int seeded = (start == 0 && masks[n] != 0.0f) ? 1 : 0;
        tasks[pos] = make_int4(n, start, len, seeded);
        start = t;
      }
    }
    const int len = TT - start;
    const int pos = atomicAdd(&offs[len], 1);
    const int seeded = (start == 0 && masks[n] != 0.0f) ? 1 : 0;
    tasks[pos] = make_int4(n, start, len, seeded);
  }
  __syncthreads();
  if (tid == 0) {
    // after pass 2, offs[l] == one-past-end index of length-l tasks
    const int c0end = offs[5];  // end of len>=5 region
    const int c1end = offs[3];  // end of len>=3 region
    int b = 0;
    for (int p = 0; p < c0end; p += 4) {
      int c = c0end - p; if (c > 4) c = 4;
      batches[b++] = make_int4(p, 4, c, 0);
    }
    for (int p = c0end; p < c1end; p += 8) {
      int c = c1end - p; if (c > 8) c = 8;
      batches[b++] = make_int4(p, 8, c, 0);
    }
    for (int p = c1end; p < totalTasks; p += 16) {
      int c = totalTasks - p; if (c > 16) c = 16;
      batches[b++] = make_int4(p, 16, c, 0);
    }
    meta[2] = b;
    meta[1] = 0;  // claim counter
  }
}

// ---------------------------------------------------------------------------
// w_hh [1536][512] -> wT [512][1536] so the recurrent dot-product loads
// (thread tid reads rows tid, tid+512, tid+1024 at column k) are coalesced.
// ---------------------------------------------------------------------------
__global__ void transpose_whh(const float* __restrict__ w, float* __restrict__ wT) {
  const int k = blockIdx.y;                       // 0..511
  const int r = blockIdx.x * 256 + threadIdx.x;   // 0..1535
  wT[k * GG + r] = w[r * DD + k];
}

// ---------------------------------------------------------------------------
// gi = x @ w_ih^T + b_ih   (fp32, 8192x1536, K=512). 128x128 tile, 8x8/thread.
// ---------------------------------------------------------------------------
__global__ __launch_bounds__(256, 4) void gemm_gi(const float* __restrict__ x,
                                                  const float* __restrict__ w,
                                                  const float* __restrict__ bias,
                                                  float* __restrict__ gi) {
  __shared__ __align__(16) float As[32][132];  // +4 pad: 16B-aligned rows, no bank conflict
  __shared__ __align__(16) float Bs[32][132];
  const int tid = threadIdx.x;
  const int m0 = blockIdx.y * 128;
  const int n0 = blockIdx.x * 128;
  const int tx = tid & 15;
  const int ty = tid >> 4;
  float acc[8][8] = {};
  for (int k0 = 0; k0 < DD; k0 += 32) {
#pragma unroll
    for (int i = 0; i < 4; ++i) {
      const int q = tid + i * 256;
      const int row = q >> 3;
      const int kf = (q & 7) << 2;
      const float4 va = *(const float4*)&x[(size_t)(m0 + row) * DD + k0 + kf];
      As[kf + 0][row] = va.x; As[kf + 1][row] = va.y;
      As[kf + 2][row] = va.z; As[kf + 3][row] = va.w;
      const float4 vb = *(const float4*)&w[(size_t)(n0 + row) * DD + k0 + kf];
      Bs[kf + 0][row] = vb.x; Bs[kf + 1][row] = vb.y;
      Bs[kf + 2][row] = vb.z; Bs[kf + 3][row] = vb.w;
    }
    __syncthreads();
#pragma unroll
    for (int k = 0; k < 32; ++k) {
      float a[8], b[8];
      ((float4*)a)[0] = *(const float4*)&As[k][ty * 8];
      ((float4*)a)[1] = *(const float4*)&As[k][ty * 8 + 4];
      ((float4*)b)[0] = *(const float4*)&Bs[k][tx * 8];
      ((float4*)b)[1] = *(const float4*)&Bs[k][tx * 8 + 4];
#pragma unroll
      for (int i = 0; i < 8; ++i)
#pragma unroll
        for (int j = 0; j < 8; ++j) acc[i][j] = fmaf(a[i], b[j], acc[i][j]);
    }
    __syncthreads();
  }
  float bs[8];
  ((float4*)bs)[0] = *(const float4*)&bias[n0 + tx * 8];
  ((float4*)bs)[1] = *(const float4*)&bias[n0 + tx * 8 + 4];
#pragma unroll
  for (int i = 0; i < 8; ++i) {
    const int row = m0 + ty * 8 + i;
    float4 o0 = make_float4(acc[i][0] + bs[0], acc[i][1] + bs[1],
                            acc[i][2] + bs[2], acc[i][3] + bs[3]);
    float4 o1 = make_float4(acc[i][4] + bs[4], acc[i][5] + bs[5],
                            acc[i][6] + bs[6], acc[i][7] + bs[7]);
    *(float4*)&gi[(size_t)row * GG + n0 + tx * 8] = o0;
    *(float4*)&gi[(size_t)row * GG + n0 + tx * 8 + 4] = o1;
  }
}

// ---------------------------------------------------------------------------
// Recurrent kernel. 512 threads: thread tid owns h-column tid, i.e. gh rows
// tid (r), 512+tid (z), 1024+tid (n) -> gate math needs no cross-thread data.
// W concurrent segments ("columns") share each w_hh element from one load.
// ---------------------------------------------------------------------------
template <int W>
__device__ __forceinline__ void process_batch(
    const float* __restrict__ gi, const float* __restrict__ wT,
    const float* __restrict__ hxs, const float* __restrict__ masks,
    float* __restrict__ out, float (*Hs)[16], const int4* s_task, int tid,
    float bh_r, float bh_z, float bh_n) {
  int t_n[W], t_t0[W], t_len[W];
  bool anySeed = false;
#pragma unroll
  for (int c = 0; c < W; ++c) {
    const int4 tk = s_task[c];
    t_n[c] = tk.x; t_t0[c] = tk.y; t_len[c] = tk.z;
    anySeed |= (tk.w != 0 && tk.z > 0);
  }
  const int maxlen = t_len[0];  // sorted descending within class
#pragma unroll
  for (int c = 0; c < W; ++c) {
    float h0 = 0.0f;
    if (s_task[c].w != 0) h0 = masks[t_n[c]] * hxs[t_n[c] * HH + tid];
    Hs[tid][c] = h0;
  }
  __syncthreads();
  for (int s = 0; s < maxlen; ++s) {
    float accr[W], accz[W], accn[W];
#pragma unroll
    for (int c = 0; c < W; ++c) { accr[c] = 0.f; accz[c] = 0.f; accn[c] = 0.f; }
    if (s > 0 || anySeed) {  // first step of zero-seeded segments: h==0 -> gh=b_hh
      const float* w = wT + tid;
#pragma unroll 4
      for (int k = 0; k < HH; ++k) {
        const float wr = w[0];
        const float wz = w[512];
        const float wn = w[1024];
        float hk[W];
        if constexpr (W >= 4)  ((float4*)hk)[0] = *(const float4*)&Hs[k][0];
        if constexpr (W >= 8)  ((float4*)hk)[1] = *(const float4*)&Hs[k][4];
        if constexpr (W >= 16) {
          ((float4*)hk)[2] = *(const float4*)&Hs[k][8];
          ((float4*)hk)[3] = *(const float4*)&Hs[k][12];
        }
#pragma unroll
        for (int c = 0; c < W; ++c) {
          accr[c] = fmaf(wr, hk[c], accr[c]);
          accz[c] = fmaf(wz, hk[c], accz[c]);
          accn[c] = fmaf(wn, hk[c], accn[c]);
        }
        w += GG;
      }
    }
    __syncthreads();  // all k-loop reads of Hs done before updates
#pragma unroll
    for (int c = 0; c < W; ++c) {
      if (s < t_len[c]) {
        const int row = (t_t0[c] + s) * NN + t_n[c];
        const float* g = gi + (size_t)row * GG + tid;
        const float gr = g[0], gz = g[512], gn = g[1024];
        const float r = 1.0f / (1.0f + expf(-(gr + accr[c] + bh_r)));
        const float z = 1.0f / (1.0f + expf(-(gz + accz[c] + bh_z)));
        const float hold = Hs[tid][c];
        const float nc = tanhf(gn + r * (accn[c] + bh_n));
        const float hnew = (1.0f - z) * nc + z * hold;
        out[(size_t)row * HH + tid] = hnew;
        Hs[tid][c] = hnew;
      }
    }
    __syncthreads();
  }
}

__global__ __launch_bounds__(512, 2) void gru_seq(
    const float* __restrict__ gi, const float* __restrict__ wT,
    const float* __restrict__ b_hh, const float* __restrict__ hxs,
    const float* __restrict__ masks, float* __restrict__ out,
    int* __restrict__ meta, const int4* __restrict__ tasks,
    const int4* __restrict__ batches) {
  __shared__ __align__(16) float Hs[HH][16];  // 32 KiB
  __shared__ int4 s_task[16];
  __shared__ int s_bidx;
  const int tid = threadIdx.x;
  const float bh_r = b_hh[tid];
  const float bh_z = b_hh[512 + tid];
  const float bh_n = b_hh[1024 + tid];
  const int nBatches = meta[2];
  while (true) {
    if (tid == 0) s_bidx = atomicAdd(&meta[1], 1);
    __syncthreads();
    const int bidx = s_bidx;
    if (bidx >= nBatches) break;
    const int4 bd = batches[bidx];
    if (tid < 16) s_task[tid] = (tid < bd.z) ? tasks[bd.x + tid] : make_int4(0, 0, 0, 0);
    __syncthreads();
    switch (bd.y) {
      case 4:
        process_batch<4>(gi, wT, hxs, masks, out, Hs, s_task, tid, bh_r, bh_z, bh_n);
        break;
      case 8:
        process_batch<8>(gi, wT, hxs, masks, out, Hs, s_task, tid, bh_r, bh_z, bh_n);
        break;
      default:
        process_batch<16>(gi, wT, hxs, masks, out, Hs, s_task, tid, bh_r, bh_z, bh_n);
        break;
    }
  }
}

// h_last = out rows [8128..8192) (contiguous), plus hxs_1 passthrough.
__global__ void tail_copy(const float4* __restrict__ src_out,
                          const float4* __restrict__ hxs1,
                          float4* __restrict__ dst) {
  const int i = blockIdx.x * 256 + threadIdx.x;  // 0..16383
  if (i < 8192)
    dst[1048576 + i] = src_out[1040384 + i];  // 8128*512/4 = 1040384
  else
    dst[1048576 + i] = hxs1[i - 8192];
}

extern "C" void kernel_launch(void* const* d_in, const int* in_sizes, int n_in,
                              void* d_out, int out_size, void* d_ws, size_t ws_size,
                              hipStream_t stream) {
  const float* x      = (const float*)d_in[0];
  const float* hxs    = (const float*)d_in[1];
  const float* hxs_1  = (const float*)d_in[2];
  const float* masks  = (const float*)d_in[3];
  const float* w_ih   = (const float*)d_in[4];
  const float* w_hh   = (const float*)d_in[5];
  const float* b_ih   = (const float*)d_in[6];
  const float* b_hh   = (const float*)d_in[7];
  float* out = (float*)d_out;
  char* ws = (char*)d_ws;
  if (ws_size < WS_NEEDED) return;  // fail loudly (validation) rather than corrupt

  int*  meta    = (int*)(ws + META_OFF);
  int4* batches = (int4*)(ws + BATCH_OFF);
  int4* tasks   = (int4*)(ws + TASK_OFF);
  float* wT     = (float*)(ws + WT_OFF);
  float* gi     = (float*)(ws + GI_OFF);

  build_tasks<<<1, 128, 0, stream>>>(masks, meta, tasks, batches);
  transpose_whh<<<dim3(6, 512), 256, 0, stream>>>(w_hh, wT);
  gemm_gi<<<dim3(12, 64), 256, 0, stream>>>(x, w_ih, b_ih, gi);
  gru_seq<<<256, 512, 0, stream>>>(gi, wT, b_hh, hxs, masks, out, meta, tasks, batches);
  tail_copy<<<64, 256, 0, stream>>>((const float4*)out, (const float4*)hxs_1,
                                    (float4*)out);
}